// Round 5
// baseline (357.908 us; speedup 1.0000x reference)
//
#include <hip/hip_runtime.h>

// Problem constants: H=W=32, HW=1024, C=512, 2C=1024, sigma=1.5 -> 2*v^2=4.5
// Single persistent kernel, 512 blocks x 256 threads, 2 blocks/CU co-resident
// (launch_bounds(256,2): ~15KB LDS, VGPR<=128 -> all 512 blocks resident).
// 5 software grid barriers over agent-scope atomics; counters zeroed by a
// captured hipMemsetAsync each iteration.

typedef short short8 __attribute__((ext_vector_type(8)));
typedef short short4v __attribute__((ext_vector_type(4)));
typedef float floatx4 __attribute__((ext_vector_type(4)));

#define NBLK 512

__device__ __forceinline__ unsigned short f2bf(float x) {
  union { float f; unsigned u; } v; v.f = x;
  unsigned u = v.u;
  u = (u + 0x7fffu + ((u >> 16) & 1u)) >> 16;   // RNE
  return (unsigned short)u;
}

__device__ __forceinline__ float block_reduce_256(float v, float* sm4) {
  #pragma unroll
  for (int off = 32; off >= 1; off >>= 1) v += __shfl_down(v, off);
  __syncthreads();
  if ((threadIdx.x & 63) == 0) sm4[threadIdx.x >> 6] = v;
  __syncthreads();
  return sm4[0] + sm4[1] + sm4[2] + sm4[3];
}

// Grid barrier: syncthreads drains all block stores to L2 (vmcnt0 before
// s_barrier); thread0 release-fences (L2 writeback to IC), arrives, spins,
// acquire-fences (L1/L2 inv). Bounded spin = hang failsafe only.
__device__ __forceinline__ void gridbar(int* cnt, int ph) {
  __syncthreads();
  if (threadIdx.x == 0) {
    __threadfence();
    __hip_atomic_fetch_add(&cnt[ph], 1, __ATOMIC_RELAXED, __HIP_MEMORY_SCOPE_AGENT);
    int it = 0;
    while (__hip_atomic_load(&cnt[ph], __ATOMIC_RELAXED, __HIP_MEMORY_SCOPE_AGENT) < NBLK) {
      __builtin_amdgcn_s_sleep(2);
      if (++it > (1 << 24)) break;
    }
    __threadfence();
  }
  __syncthreads();
}

__global__ __launch_bounds__(256, 2) void k_fused(
    const float* __restrict__ x, const float* __restrict__ w1,
    const float* __restrict__ w2, const float* __restrict__ wdn,
    int* __restrict__ cnt, float* __restrict__ smean,
    float* __restrict__ out32T, float* __restrict__ sigT,
    float* __restrict__ V, float* __restrict__ T1,
    unsigned short* __restrict__ catT, unsigned short* __restrict__ Abf,
    float* __restrict__ yp, float* __restrict__ out) {
  __shared__ float sm4[4];
  __shared__ float sm[512];
  __shared__ float s1[32];
  __shared__ float sc[32];
  __shared__ float tile[32][33];
  __shared__ float g[1024];
  __shared__ float vrow[1024];

  const int tid = threadIdx.x;
  const int b = blockIdx.x;

  // ---- Phase A: per-channel mean (block b = channel b) + w_down -> bf16 ----
  {
    const float* row = x + b * 1024;
    float s = 0.0f;
    #pragma unroll
    for (int i = tid; i < 1024; i += 256) s += row[i];
    float t = block_reduce_256(s, sm4);
    if (tid == 0) smean[b] = t * (1.0f / 1024.0f);
    int base = b * 1024 + tid * 4;
    float4 a4 = *(const float4*)&wdn[base];
    short4v s4;
    s4[0] = (short)f2bf(a4.x); s4[1] = (short)f2bf(a4.y);
    s4[2] = (short)f2bf(a4.z); s4[3] = (short)f2bf(a4.w);
    *(short4v*)&Abf[base] = s4;
    // gaussian 1D weights into LDS (persist across phases C/D)
    int ga = tid >> 3, gb0 = (tid & 7) * 4;
    float e[4]; float gs = 0.0f;
    #pragma unroll
    for (int q = 0; q < 4; q++) {
      float d = (float)(ga - (gb0 + q));
      e[q] = __expf(d * d * (-1.0f / 4.5f));
      gs += e[q];
    }
    gs += __shfl_xor(gs, 1, 8);
    gs += __shfl_xor(gs, 2, 8);
    gs += __shfl_xor(gs, 4, 8);
    float ginv = 1.0f / gs;
    #pragma unroll
    for (int q = 0; q < 4; q++) g[ga * 32 + gb0 + q] = e[q] * ginv;
  }
  gridbar(cnt, 0);

  // ---- Phase B: SE (redundant per block) + scale + transposes ----
  {
    for (int i = tid; i < 512; i += 256) sm[i] = smean[i];
    __syncthreads();
    int j = tid >> 3, l8 = tid & 7;
    float a = 0.0f;
    for (int cc = l8; cc < 512; cc += 8) a += sm[cc] * w1[j * 512 + cc];
    a += __shfl_down(a, 4, 8);
    a += __shfl_down(a, 2, 8);
    a += __shfl_down(a, 1, 8);
    if (l8 == 0) s1[j] = fmaxf(a, 0.0f);
    __syncthreads();
    int c0 = (b & 15) * 32, hw0 = (b >> 4) * 32;
    if (tid < 32) {
      float bb = 0.0f;
      #pragma unroll
      for (int jj = 0; jj < 32; jj++) bb += s1[jj] * w2[(c0 + tid) * 32 + jj];
      sc[tid] = 1.0f / (1.0f + __expf(-bb));
    }
    __syncthreads();
    int tx = tid & 31, ty = tid >> 5;
    #pragma unroll
    for (int r = 0; r < 4; r++) {
      int c = ty + 8 * r;
      tile[c][tx] = x[(c0 + c) * 1024 + hw0 + tx] * sc[c];
    }
    __syncthreads();
    #pragma unroll
    for (int r = 0; r < 4; r++) {
      int hw = hw0 + ty + 8 * r;
      float v = tile[tx][ty + 8 * r];
      out32T[hw * 512 + c0 + tx] = v;
      sigT[hw * 512 + c0 + tx] = 1.0f / (1.0f + __expf(-v));
      int hwsw = ((hw & 31) << 5) | (hw >> 5);   // V[(y,x)][c] = out32[c][x,y]
      V[hwsw * 512 + c0 + tx] = v;
    }
  }
  gridbar(cnt, 1);

  // ---- Phase C: gauss pass1 T1[(k,x)][c] + CSA (waves 0-1, p = 2b+wv) ----
  {
    int t = b * 256 + tid;
    int c = t & 511;
    int xk = t >> 9;                 // 0..255
    int xx = xk & 31, kg = xk >> 5;  // k0 = kg*4
    const float* vp = V + xx * 512 + c;
    const float* g0 = g + kg * 128;
    float s0 = 0, s1v = 0, s2 = 0, s3 = 0;
    #pragma unroll 8
    for (int y = 0; y < 32; y++) {
      float vv = vp[y * 16384];
      s0 += g0[y] * vv;
      s1v += g0[32 + y] * vv;
      s2 += g0[64 + y] * vv;
      s3 += g0[96 + y] * vv;
    }
    int ko = kg * 128 + xx;          // (k*32 + x)
    T1[ko * 512 + c] = s0;
    T1[(ko + 32) * 512 + c] = s1v;
    T1[(ko + 64) * 512 + c] = s2;
    T1[(ko + 96) * 512 + c] = s3;

    int wv = tid >> 6, lane = tid & 63;
    if (wv < 2) {
      int p = b * 2 + wv;
      int h = p >> 5, w = p & 31;
      int c0 = lane * 8;
      float4 ce0 = *(const float4*)&sigT[p * 512 + c0];
      float4 ce1 = *(const float4*)&sigT[p * 512 + c0 + 4];
      int qoff[9];
      float s[9];
      #pragma unroll
      for (int dd = 0; dd < 9; dd++) {
        int hh = h + dd / 3 - 1, ww = w + (dd % 3) - 1;
        bool v = (hh >= 0) && (hh < 32) && (ww >= 0) && (ww < 32);
        qoff[dd] = v ? (hh * 32 + ww) * 512 : -1;
        float a = 0.0f;
        if (v) {
          float4 n0 = *(const float4*)&sigT[qoff[dd] + c0];
          float4 n1 = *(const float4*)&sigT[qoff[dd] + c0 + 4];
          a = ce0.x * n0.x + ce0.y * n0.y + ce0.z * n0.z + ce0.w * n0.w
            + ce1.x * n1.x + ce1.y * n1.y + ce1.z * n1.z + ce1.w * n1.w;
        }
        #pragma unroll
        for (int off = 32; off >= 1; off >>= 1) a += __shfl_xor(a, off);
        s[dd] = a;
      }
      float mx = -1e30f;
      #pragma unroll
      for (int dd = 0; dd < 9; dd++) { s[dd] *= (1.0f / 512.0f); mx = fmaxf(mx, s[dd]); }
      float tot = 0.0f;
      #pragma unroll
      for (int dd = 0; dd < 9; dd++) { s[dd] = __expf(s[dd] - mx); tot += s[dd]; }
      float inv = 1.0f / tot;
      float o[8] = {0, 0, 0, 0, 0, 0, 0, 0};
      #pragma unroll
      for (int dd = 0; dd < 9; dd++) {
        if (qoff[dd] >= 0) {
          float att = s[dd] * inv;
          float4 r0 = *(const float4*)&out32T[qoff[dd] + c0];
          float4 r1 = *(const float4*)&out32T[qoff[dd] + c0 + 4];
          o[0] += att * r0.x; o[1] += att * r0.y; o[2] += att * r0.z; o[3] += att * r0.w;
          o[4] += att * r1.x; o[5] += att * r1.y; o[6] += att * r1.z; o[7] += att * r1.w;
        }
      }
      // flat f = 524288 + p*512 + c -> catT[n=(p&1)*512+c][k=512+(p>>1)]
      int kcol = 512 + (p >> 1);
      int nbase = (p & 1) * 512 + c0;
      #pragma unroll
      for (int q = 0; q < 8; q++) catT[(nbase + q) * 1024 + kcol] = f2bf(o[q]);
    }
  }
  gridbar(cnt, 2);

  // ---- Phase D: gauss pass2 -> catT bf16 left half ----
  {
    int t = b * 256 + tid;
    int c = t & 511;
    int rest = t >> 9;           // 0..255
    int i = rest >> 3;           // 0..31
    int sub = rest & 7;
    int par = sub & 1, kq = sub >> 1;
    int kb = kq * 8 + par;
    const float* tp = T1 + c;
    const float* gi = g + i * 32;
    float s0 = 0, s1v = 0, s2 = 0, s3 = 0;
    #pragma unroll 8
    for (int xx = 0; xx < 32; xx++) {
      float gv = gi[xx];
      s0 += gv * tp[((kb + 0) * 32 + xx) * 512];
      s1v += gv * tp[((kb + 2) * 32 + xx) * 512];
      s2 += gv * tp[((kb + 4) * 32 + xx) * 512];
      s3 += gv * tp[((kb + 6) * 32 + xx) * 512];
    }
    short4v o;
    o[0] = (short)f2bf(s0); o[1] = (short)f2bf(s1v);
    o[2] = (short)f2bf(s2); o[3] = (short)f2bf(s3);
    *(short4v*)&catT[(par * 512 + c) * 1024 + i * 16 + kq * 4] = o;
  }
  gridbar(cnt, 3);

  // ---- Phase E: bf16 MFMA GEMM, wave tile M16xN32, split-K 2 ----
  {
    int wv = tid >> 6, lane = tid & 63;
    int m = b >> 4;                  // 0..31
    int nn = (b & 15) * 64 + (wv & 1) * 32;
    int kz = wv >> 1;
    int l16 = lane & 15, quad = lane >> 4;
    const short8* ap  = (const short8*)(Abf + (m * 16 + l16) * 1024 + kz * 512 + quad * 8);
    const short8* bp0 = (const short8*)(catT + (nn + l16) * 1024 + kz * 512 + quad * 8);
    const short8* bp1 = (const short8*)(catT + (nn + 16 + l16) * 1024 + kz * 512 + quad * 8);
    floatx4 acc0 = {0.f, 0.f, 0.f, 0.f}, acc1 = {0.f, 0.f, 0.f, 0.f};
    #pragma unroll 4
    for (int kk = 0; kk < 16; kk++) {
      short8 a  = ap[kk * 4];
      short8 b0 = bp0[kk * 4];
      short8 b1 = bp1[kk * 4];
      acc0 = __builtin_amdgcn_mfma_f32_16x16x32_bf16(a, b0, acc0, 0, 0, 0);
      acc1 = __builtin_amdgcn_mfma_f32_16x16x32_bf16(a, b1, acc1, 0, 0, 0);
    }
    float* yo = yp + kz * 524288 + (m * 16 + quad * 4) * 1024 + l16;
    #pragma unroll
    for (int r = 0; r < 4; r++) {
      yo[r * 1024 + nn] = acc0[r];
      yo[r * 1024 + nn + 16] = acc1[r];
    }
  }
  gridbar(cnt, 4);

  // ---- Phase F: sum split-K + instance norm + LeakyReLU(0.2) ----
  {
    const float* r0 = yp + b * 1024;
    float s = 0.0f, q = 0.0f;
    for (int i = tid; i < 1024; i += 256) {
      float v = r0[i] + r0[i + 524288];
      vrow[i] = v;
      s += v; q += v * v;
    }
    float ts = block_reduce_256(s, sm4);
    float tq = block_reduce_256(q, sm4);
    float mean = ts * (1.0f / 1024.0f);
    float var = tq * (1.0f / 1024.0f) - mean * mean;
    float inv = rsqrtf(var + 1e-5f);
    for (int i = tid; i < 1024; i += 256) {
      float v = (vrow[i] - mean) * inv;
      out[b * 1024 + i] = v >= 0.0f ? v : 0.2f * v;
    }
  }
}

extern "C" void kernel_launch(void* const* d_in, const int* in_sizes, int n_in,
                              void* d_out, int out_size, void* d_ws, size_t ws_size,
                              hipStream_t stream) {
  const float* x      = (const float*)d_in[0];  // (1,512,32,32)
  const float* w_se1  = (const float*)d_in[1];  // (32,512)
  const float* w_se2  = (const float*)d_in[2];  // (512,32)
  const float* w_down = (const float*)d_in[3];  // (512,1024,1,1)
  float* out = (float*)d_out;                   // (1,512,32,32)

  float* ws = (float*)d_ws;
  int*   cnt    = (int*)ws;                  // 16 ints (zeroed below)
  float* smean  = ws + 1024;                 // 512
  float* out32T = ws + 2048;                 // 524288  [hw][c]
  float* sigT   = ws + 526336;               // 524288  [hw][c]
  float* V      = ws + 1050624;              // 524288  [(y,x)][c]
  float* T1     = ws + 1574912;              // 524288  [(k,x)][c]
  unsigned short* catT = (unsigned short*)(ws + 2099200);  // 1024x1024 bf16 [n][k]
  unsigned short* Abf  = (unsigned short*)(ws + 2623488);  // 512x1024 bf16
  float* yp     = ws + 2885632;              // 2 x 524288 split-K partials

  hipMemsetAsync(cnt, 0, 64, stream);        // zero barrier counters (captured)
  k_fused<<<NBLK, 256, 0, stream>>>(x, w_se1, w_se2, w_down, cnt, smean,
                                    out32T, sigT, V, T1, catT, Abf, yp, out);
}

// Round 6
// 102.817 us; speedup vs baseline: 3.4810x; 3.4810x over previous
//
#include <hip/hip_runtime.h>

// Problem constants: H=W=32, HW=1024, C=512, 2C=1024, sigma=1.5 -> 2*v^2=4.5
// R6: multi-kernel (grid barriers cost ~50us/each on MI355X - reverted), 5 dispatches:
//   k_mean_cvt -> k_apply -> k_gausscsa -> k_gemm -> k_inorm

typedef short short8 __attribute__((ext_vector_type(8)));
typedef short short4v __attribute__((ext_vector_type(4)));
typedef float floatx4 __attribute__((ext_vector_type(4)));
typedef float floatx16 __attribute__((ext_vector_type(16)));

__device__ __forceinline__ unsigned short f2bf(float x) {
  union { float f; unsigned u; } v; v.f = x;
  unsigned u = v.u;
  u = (u + 0x7fffu + ((u >> 16) & 1u)) >> 16;   // RNE
  return (unsigned short)u;
}

__device__ __forceinline__ float block_reduce_256(float v, float* sm4) {
  #pragma unroll
  for (int off = 32; off >= 1; off >>= 1) v += __shfl_down(v, off);
  __syncthreads();
  if ((threadIdx.x & 63) == 0) sm4[threadIdx.x >> 6] = v;
  __syncthreads();
  return sm4[0] + sm4[1] + sm4[2] + sm4[3];
}

// Compute normalized 1D gaussian g[32][32] into LDS (256 threads, 4 cols each).
__device__ __forceinline__ void gauss_lds(float* g, int tid) {
  int ga = tid >> 3, gb0 = (tid & 7) * 4;
  float e[4]; float gs = 0.0f;
  #pragma unroll
  for (int q = 0; q < 4; q++) {
    float d = (float)(ga - (gb0 + q));
    e[q] = __expf(d * d * (-1.0f / 4.5f));
    gs += e[q];
  }
  gs += __shfl_xor(gs, 1, 8);
  gs += __shfl_xor(gs, 2, 8);
  gs += __shfl_xor(gs, 4, 8);
  float ginv = 1.0f / gs;
  #pragma unroll
  for (int q = 0; q < 4; q++) g[ga * 32 + gb0 + q] = e[q] * ginv;
}

// --- K1: blocks 0..511 per-channel mean of x; blocks 512..767 w_down -> bf16 ---
__global__ void k_mean_cvt(const float* __restrict__ x, float* __restrict__ smean,
                           const float* __restrict__ wdn, unsigned short* __restrict__ Abf) {
  if (blockIdx.x >= 512) {
    int base = (blockIdx.x - 512) * 2048 + threadIdx.x * 8;
    float4 a = *(const float4*)&wdn[base];
    float4 b = *(const float4*)&wdn[base + 4];
    short8 s;
    s[0] = (short)f2bf(a.x); s[1] = (short)f2bf(a.y); s[2] = (short)f2bf(a.z); s[3] = (short)f2bf(a.w);
    s[4] = (short)f2bf(b.x); s[5] = (short)f2bf(b.y); s[6] = (short)f2bf(b.z); s[7] = (short)f2bf(b.w);
    *(short8*)&Abf[base] = s;
    return;
  }
  __shared__ float sm4[4];
  int c = blockIdx.x;
  const float* row = x + c * 1024;
  float s = 0.0f;
  for (int i = threadIdx.x; i < 1024; i += 256) s += row[i];
  float t = block_reduce_256(s, sm4);
  if (threadIdx.x == 0) smean[c] = t * (1.0f / 1024.0f);
}

// --- K2: SE (redundant per block) + scale; writes out32 (c-major), out32T, sigT ---
__global__ void k_apply(const float* __restrict__ x, const float* __restrict__ smean,
                        const float* __restrict__ w1, const float* __restrict__ w2,
                        float* __restrict__ out32, float* __restrict__ out32T,
                        float* __restrict__ sigT) {
  __shared__ float sm[512];
  __shared__ float s1[32];
  __shared__ float sc[32];
  __shared__ float tile[32][33];
  int tid = threadIdx.x;
  for (int i = tid; i < 512; i += 256) sm[i] = smean[i];
  __syncthreads();
  int j = tid >> 3, l8 = tid & 7;
  float a = 0.0f;
  for (int cc = l8; cc < 512; cc += 8) a += sm[cc] * w1[j * 512 + cc];
  a += __shfl_down(a, 4, 8);
  a += __shfl_down(a, 2, 8);
  a += __shfl_down(a, 1, 8);
  if (l8 == 0) s1[j] = fmaxf(a, 0.0f);
  __syncthreads();
  int c0 = blockIdx.y * 32, hw0 = blockIdx.x * 32;
  if (tid < 32) {
    float bb = 0.0f;
    #pragma unroll
    for (int jj = 0; jj < 32; jj++) bb += s1[jj] * w2[(c0 + tid) * 32 + jj];
    sc[tid] = 1.0f / (1.0f + __expf(-bb));
  }
  __syncthreads();
  int tx = tid & 31, ty = tid >> 5;
  #pragma unroll
  for (int r = 0; r < 4; r++) {
    int c = ty + 8 * r;
    float v = x[(c0 + c) * 1024 + hw0 + tx] * sc[c];
    out32[(c0 + c) * 1024 + hw0 + tx] = v;
    tile[c][tx] = v;
  }
  __syncthreads();
  #pragma unroll
  for (int r = 0; r < 4; r++) {
    int hw = hw0 + ty + 8 * r;
    float v = tile[tx][ty + 8 * r];
    out32T[hw * 512 + c0 + tx] = v;
    sigT[hw * 512 + c0 + tx] = 1.0f / (1.0f + __expf(-v));
  }
}

// --- K3: blocks 0..511: full separable gauss for channel c (both passes in LDS)
//         -> catT bf16 left half;  blocks 512..767: CSA -> catT bf16 right half ---
__global__ void k_gausscsa(const float* __restrict__ out32, const float* __restrict__ sigT,
                           const float* __restrict__ out32T, unsigned short* __restrict__ catT) {
  if (blockIdx.x < 512) {
    __shared__ float g[1024];
    __shared__ float row[32 * 33];   // [x][y] padded
    __shared__ float T[32 * 33];     // [k][x] padded
    int c = blockIdx.x;
    int tid = threadIdx.x;
    gauss_lds(g, tid);
    for (int idx = tid; idx < 1024; idx += 256)
      row[(idx >> 5) * 33 + (idx & 31)] = out32[c * 1024 + idx];
    __syncthreads();
    // pass 1 (over y): T[k][x] = sum_y g[k,y]*row[x,y]; thread: x = tid&31, k = kg*4+j
    {
      int xx = tid & 31, kg = tid >> 5;
      const float* g0 = g + kg * 128;
      const float* rw = row + xx * 33;
      float s0 = 0, s1 = 0, s2 = 0, s3 = 0;
      #pragma unroll 8
      for (int y = 0; y < 32; y++) {
        float vv = rw[y];
        s0 += g0[y] * vv;
        s1 += g0[32 + y] * vv;
        s2 += g0[64 + y] * vv;
        s3 += g0[96 + y] * vv;
      }
      int k0 = kg * 4;
      T[(k0 + 0) * 33 + xx] = s0;
      T[(k0 + 1) * 33 + xx] = s1;
      T[(k0 + 2) * 33 + xx] = s2;
      T[(k0 + 3) * 33 + xx] = s3;
    }
    __syncthreads();
    // pass 2 (over x): S[i,k] = sum_x g[i,x]*T[k,x]; pack 4 same-parity k per thread
    {
      int i = tid >> 3;
      int sub = tid & 7;
      int par = sub & 1, kq = sub >> 1;
      int kb = kq * 8 + par;            // k = kb + 2j, j=0..3
      const float* gi = g + i * 32;
      float s0 = 0, s1 = 0, s2 = 0, s3 = 0;
      #pragma unroll 8
      for (int xx = 0; xx < 32; xx++) {
        float gv = gi[xx];
        s0 += gv * T[(kb + 0) * 33 + xx];
        s1 += gv * T[(kb + 2) * 33 + xx];
        s2 += gv * T[(kb + 4) * 33 + xx];
        s3 += gv * T[(kb + 6) * 33 + xx];
      }
      // flat f = p*512+c, p=i*32+k -> catT[n=(par*512+c)][col=i*16+kq*4+j]
      short4v o;
      o[0] = (short)f2bf(s0); o[1] = (short)f2bf(s1);
      o[2] = (short)f2bf(s2); o[3] = (short)f2bf(s3);
      *(short4v*)&catT[(par * 512 + c) * 1024 + i * 16 + kq * 4] = o;
    }
  } else {
    // CSA: one wave per location p
    int wv = threadIdx.x >> 6;
    int lane = threadIdx.x & 63;
    int p = (blockIdx.x - 512) * 4 + wv;
    int h = p >> 5, w = p & 31;
    int c0 = lane * 8;
    float4 ce0 = *(const float4*)&sigT[p * 512 + c0];
    float4 ce1 = *(const float4*)&sigT[p * 512 + c0 + 4];
    int qoff[9];
    float s[9];
    #pragma unroll
    for (int dd = 0; dd < 9; dd++) {
      int hh = h + dd / 3 - 1, ww = w + (dd % 3) - 1;
      bool v = (hh >= 0) && (hh < 32) && (ww >= 0) && (ww < 32);
      qoff[dd] = v ? (hh * 32 + ww) * 512 : -1;
      float a = 0.0f;
      if (v) {
        float4 n0 = *(const float4*)&sigT[qoff[dd] + c0];
        float4 n1 = *(const float4*)&sigT[qoff[dd] + c0 + 4];
        a = ce0.x * n0.x + ce0.y * n0.y + ce0.z * n0.z + ce0.w * n0.w
          + ce1.x * n1.x + ce1.y * n1.y + ce1.z * n1.z + ce1.w * n1.w;
      }
      #pragma unroll
      for (int off = 32; off >= 1; off >>= 1) a += __shfl_xor(a, off);
      s[dd] = a;
    }
    float mx = -1e30f;
    #pragma unroll
    for (int dd = 0; dd < 9; dd++) { s[dd] *= (1.0f / 512.0f); mx = fmaxf(mx, s[dd]); }
    float tot = 0.0f;
    #pragma unroll
    for (int dd = 0; dd < 9; dd++) { s[dd] = __expf(s[dd] - mx); tot += s[dd]; }
    float inv = 1.0f / tot;
    float o[8] = {0, 0, 0, 0, 0, 0, 0, 0};
    #pragma unroll
    for (int dd = 0; dd < 9; dd++) {
      if (qoff[dd] >= 0) {
        float att = s[dd] * inv;
        float4 r0 = *(const float4*)&out32T[qoff[dd] + c0];
        float4 r1 = *(const float4*)&out32T[qoff[dd] + c0 + 4];
        o[0] += att * r0.x; o[1] += att * r0.y; o[2] += att * r0.z; o[3] += att * r0.w;
        o[4] += att * r1.x; o[5] += att * r1.y; o[6] += att * r1.z; o[7] += att * r1.w;
      }
    }
    // flat f = 524288 + p*512 + c -> catT[n=(p&1)*512+c][col=512+(p>>1)]
    int kcol = 512 + (p >> 1);
    int nbase = (p & 1) * 512 + c0;
    #pragma unroll
    for (int q = 0; q < 8; q++) catT[(nbase + q) * 1024 + kcol] = f2bf(o[q]);
  }
}

// --- K4: bf16 MFMA GEMM y[512][1024] = Abf x catT^T, 32x32x16 MFMA ---
// 256 blocks x 4 waves: block = M32 x N64; wave = (ntile, kz); kz pair summed via LDS.
__global__ void k_gemm(const unsigned short* __restrict__ Abf,
                       const unsigned short* __restrict__ Bbf,
                       float* __restrict__ y) {
  __shared__ float red[2][1024];   // per-ntile kz1 partials
  int tid = threadIdx.x;
  int wv = tid >> 6, lane = tid & 63;
  int nt = wv & 1, kz = wv >> 1;
  int bm = (blockIdx.x >> 4) * 32;
  int nn = (blockIdx.x & 15) * 64 + nt * 32;
  int l32 = lane & 31, half = lane >> 5;
  const short8* ap = (const short8*)(Abf + (bm + l32) * 1024 + kz * 512 + half * 8);
  const short8* bp = (const short8*)(Bbf + (nn + l32) * 1024 + kz * 512 + half * 8);
  floatx16 acc = {};
  #pragma unroll 8
  for (int ks = 0; ks < 32; ks++) {
    short8 a = ap[ks * 2];          // 16 k per step, halves interleaved
    short8 b = bp[ks * 2];
    acc = __builtin_amdgcn_mfma_f32_32x32x16_bf16(a, b, acc, 0, 0, 0);
  }
  if (kz == 1) {
    #pragma unroll
    for (int r = 0; r < 16; r++) red[nt][lane * 16 + r] = acc[r];
  }
  __syncthreads();
  if (kz == 0) {
    // C/D layout: col = lane&31, row = (reg&3) + 8*(reg>>2) + 4*half
    #pragma unroll
    for (int r = 0; r < 16; r++) {
      float v = acc[r] + red[nt][lane * 16 + r];
      int rowm = (r & 3) + 8 * (r >> 2) + 4 * half;
      y[(bm + rowm) * 1024 + nn + l32] = v;
    }
  }
}

// --- K5: instance norm (biased var) + LeakyReLU(0.2) ---
__global__ void k_inorm(const float* __restrict__ y, float* __restrict__ out) {
  __shared__ float sm4[4];
  __shared__ float vrow[1024];
  int o = blockIdx.x;
  const float* r0 = y + o * 1024;
  float s = 0.0f, q = 0.0f;
  for (int i = threadIdx.x; i < 1024; i += 256) {
    float v = r0[i];
    vrow[i] = v;
    s += v; q += v * v;
  }
  float ts = block_reduce_256(s, sm4);
  float tq = block_reduce_256(q, sm4);
  float mean = ts * (1.0f / 1024.0f);
  float var = tq * (1.0f / 1024.0f) - mean * mean;
  float inv = rsqrtf(var + 1e-5f);
  for (int i = threadIdx.x; i < 1024; i += 256) {
    float v = (vrow[i] - mean) * inv;
    out[o * 1024 + i] = v >= 0.0f ? v : 0.2f * v;
  }
}

extern "C" void kernel_launch(void* const* d_in, const int* in_sizes, int n_in,
                              void* d_out, int out_size, void* d_ws, size_t ws_size,
                              hipStream_t stream) {
  const float* x      = (const float*)d_in[0];  // (1,512,32,32)
  const float* w_se1  = (const float*)d_in[1];  // (32,512)
  const float* w_se2  = (const float*)d_in[2];  // (512,32)
  const float* w_down = (const float*)d_in[3];  // (512,1024,1,1)
  float* out = (float*)d_out;                   // (1,512,32,32)

  float* ws = (float*)d_ws;
  float* smean  = ws;                        // 512 (+pad to 1024)
  float* out32  = ws + 1024;                 // 524288  [c][hw]
  float* out32T = ws + 525312;               // 524288  [hw][c]
  float* sigT   = ws + 1049600;              // 524288  [hw][c]
  unsigned short* catT = (unsigned short*)(ws + 1573888);  // 1024x1024 bf16 [n][k]
  unsigned short* Abf  = (unsigned short*)(ws + 2098176);  // 512x1024 bf16 [m][k]
  float* ybuf   = ws + 2360320;              // 524288

  k_mean_cvt<<<768, 256, 0, stream>>>(x, smean, w_down, Abf);
  k_apply<<<dim3(32, 16), 256, 0, stream>>>(x, smean, w_se1, w_se2, out32, out32T, sigT);
  k_gausscsa<<<768, 256, 0, stream>>>(out32, sigT, out32T, catT);
  k_gemm<<<256, 256, 0, stream>>>(Abf, catT, ybuf);
  k_inorm<<<512, 256, 0, stream>>>(ybuf, out);
}

// Round 7
// 100.307 us; speedup vs baseline: 3.5681x; 1.0250x over previous
//
#include <hip/hip_runtime.h>

// Problem constants: H=W=32, HW=1024, C=512, 2C=1024, sigma=1.5 -> 2*v^2=4.5
// 5 dispatches (provable minimum given grid-wide deps; software grid barriers
// measured ~50us each on MI355X in R5 - 10x worse than a launch boundary):
//   k_mean_cvt -> k_apply -> k_gausscsa -> k_gemm -> k_inorm
// Fixed floor: harness re-poisons 268MB d_ws twice (~83us @ 80% HBM peak).

typedef short short8 __attribute__((ext_vector_type(8)));
typedef short short4v __attribute__((ext_vector_type(4)));
typedef float floatx4 __attribute__((ext_vector_type(4)));
typedef float floatx16 __attribute__((ext_vector_type(16)));

__device__ __forceinline__ unsigned short f2bf(float x) {
  union { float f; unsigned u; } v; v.f = x;
  unsigned u = v.u;
  u = (u + 0x7fffu + ((u >> 16) & 1u)) >> 16;   // RNE
  return (unsigned short)u;
}

__device__ __forceinline__ float dot4(float4 a, float4 b) {
  return a.x * b.x + a.y * b.y + a.z * b.z + a.w * b.w;
}

__device__ __forceinline__ float block_reduce_256(float v, float* sm4) {
  #pragma unroll
  for (int off = 32; off >= 1; off >>= 1) v += __shfl_down(v, off);
  __syncthreads();
  if ((threadIdx.x & 63) == 0) sm4[threadIdx.x >> 6] = v;
  __syncthreads();
  return sm4[0] + sm4[1] + sm4[2] + sm4[3];
}

// Compute normalized 1D gaussian g[32][32] into LDS (256 threads, 4 cols each).
__device__ __forceinline__ void gauss_lds(float* g, int tid) {
  int ga = tid >> 3, gb0 = (tid & 7) * 4;
  float e[4]; float gs = 0.0f;
  #pragma unroll
  for (int q = 0; q < 4; q++) {
    float d = (float)(ga - (gb0 + q));
    e[q] = __expf(d * d * (-1.0f / 4.5f));
    gs += e[q];
  }
  gs += __shfl_xor(gs, 1, 8);
  gs += __shfl_xor(gs, 2, 8);
  gs += __shfl_xor(gs, 4, 8);
  float ginv = 1.0f / gs;
  #pragma unroll
  for (int q = 0; q < 4; q++) g[ga * 32 + gb0 + q] = e[q] * ginv;
}

// --- K1: blocks 0..511 per-channel mean of x; blocks 512..767 w_down -> bf16 ---
__global__ void k_mean_cvt(const float* __restrict__ x, float* __restrict__ smean,
                           const float* __restrict__ wdn, unsigned short* __restrict__ Abf) {
  if (blockIdx.x >= 512) {
    int base = (blockIdx.x - 512) * 2048 + threadIdx.x * 8;
    float4 a = *(const float4*)&wdn[base];
    float4 b = *(const float4*)&wdn[base + 4];
    short8 s;
    s[0] = (short)f2bf(a.x); s[1] = (short)f2bf(a.y); s[2] = (short)f2bf(a.z); s[3] = (short)f2bf(a.w);
    s[4] = (short)f2bf(b.x); s[5] = (short)f2bf(b.y); s[6] = (short)f2bf(b.z); s[7] = (short)f2bf(b.w);
    *(short8*)&Abf[base] = s;
    return;
  }
  __shared__ float sm4[4];
  int c = blockIdx.x;
  const float4* row = (const float4*)(x + c * 1024);
  float4 v = row[threadIdx.x];
  float s = v.x + v.y + v.z + v.w;
  float t = block_reduce_256(s, sm4);
  if (threadIdx.x == 0) smean[c] = t * (1.0f / 1024.0f);
}

// --- K2: SE (redundant per block) + scale; writes out32 (c-major), out32T, sigT ---
__global__ void k_apply(const float* __restrict__ x, const float* __restrict__ smean,
                        const float* __restrict__ w1, const float* __restrict__ w2,
                        float* __restrict__ out32, float* __restrict__ out32T,
                        float* __restrict__ sigT) {
  __shared__ float sm[512];
  __shared__ float s1[32];
  __shared__ float sc[32];
  __shared__ float tile[32][33];
  int tid = threadIdx.x;
  for (int i = tid; i < 512; i += 256) sm[i] = smean[i];
  __syncthreads();
  int j = tid >> 3, l8 = tid & 7;
  float a = 0.0f;
  for (int cc = l8; cc < 512; cc += 8) a += sm[cc] * w1[j * 512 + cc];
  a += __shfl_down(a, 4, 8);
  a += __shfl_down(a, 2, 8);
  a += __shfl_down(a, 1, 8);
  if (l8 == 0) s1[j] = fmaxf(a, 0.0f);
  __syncthreads();
  int c0 = blockIdx.y * 32, hw0 = blockIdx.x * 32;
  if (tid < 32) {
    float bb = 0.0f;
    #pragma unroll
    for (int jj = 0; jj < 32; jj++) bb += s1[jj] * w2[(c0 + tid) * 32 + jj];
    sc[tid] = 1.0f / (1.0f + __expf(-bb));
  }
  __syncthreads();
  int tx = tid & 31, ty = tid >> 5;
  #pragma unroll
  for (int r = 0; r < 4; r++) {
    int c = ty + 8 * r;
    float v = x[(c0 + c) * 1024 + hw0 + tx] * sc[c];
    out32[(c0 + c) * 1024 + hw0 + tx] = v;
    tile[c][tx] = v;
  }
  __syncthreads();
  #pragma unroll
  for (int r = 0; r < 4; r++) {
    int hw = hw0 + ty + 8 * r;
    float v = tile[tx][ty + 8 * r];
    out32T[hw * 512 + c0 + tx] = v;
    sigT[hw * 512 + c0 + tx] = 1.0f / (1.0f + __expf(-v));
  }
}

// --- K3: blocks 0..511: full separable gauss for channel c (both passes in LDS,
//         pad-36 rows for b128 LDS reads) -> catT bf16 left half;
//         blocks 512..767: CSA -> catT bf16 right half ---
__global__ void k_gausscsa(const float* __restrict__ out32, const float* __restrict__ sigT,
                           const float* __restrict__ out32T, unsigned short* __restrict__ catT) {
  if (blockIdx.x < 512) {
    __shared__ float g[1024];        // [k][y], rows 128B (b128-aligned)
    __shared__ float row[32 * 36];   // [x][y] pad 36 (144B rows, b128-aligned)
    __shared__ float T[32 * 36];     // [k][x] pad 36
    int c = blockIdx.x;
    int tid = threadIdx.x;
    gauss_lds(g, tid);
    {   // stage channel map as float4: thread -> (x = tid>>3, y4 = tid&7)
      int xx = tid >> 3, y4 = tid & 7;
      float4 v = *(const float4*)&out32[c * 1024 + xx * 32 + y4 * 4];
      *(float4*)&row[xx * 36 + y4 * 4] = v;
    }
    __syncthreads();
    // pass 1 (over y): T[k][x] = sum_y g[k,y]*row[x,y]; thread: x = tid&31, k = kg*4+j
    {
      int xx = tid & 31, kg = tid >> 5;
      int k0 = kg * 4;
      const float4* rw4 = (const float4*)(row + xx * 36);
      float s0 = 0, s1 = 0, s2 = 0, s3 = 0;
      #pragma unroll
      for (int y4 = 0; y4 < 8; y4++) {
        float4 rv = rw4[y4];
        s0 += dot4(*(const float4*)&g[(k0 + 0) * 32 + y4 * 4], rv);
        s1 += dot4(*(const float4*)&g[(k0 + 1) * 32 + y4 * 4], rv);
        s2 += dot4(*(const float4*)&g[(k0 + 2) * 32 + y4 * 4], rv);
        s3 += dot4(*(const float4*)&g[(k0 + 3) * 32 + y4 * 4], rv);
      }
      T[(k0 + 0) * 36 + xx] = s0;
      T[(k0 + 1) * 36 + xx] = s1;
      T[(k0 + 2) * 36 + xx] = s2;
      T[(k0 + 3) * 36 + xx] = s3;
    }
    __syncthreads();
    // pass 2 (over x): S[i,k] = sum_x g[i,x]*T[k,x]; 4 same-parity k per thread
    {
      int i = tid >> 3;
      int sub = tid & 7;
      int par = sub & 1, kq = sub >> 1;
      int kb = kq * 8 + par;            // k = kb + 2j, j=0..3
      float s0 = 0, s1 = 0, s2 = 0, s3 = 0;
      #pragma unroll
      for (int x4 = 0; x4 < 8; x4++) {
        float4 gv = *(const float4*)&g[i * 32 + x4 * 4];
        s0 += dot4(gv, *(const float4*)&T[(kb + 0) * 36 + x4 * 4]);
        s1 += dot4(gv, *(const float4*)&T[(kb + 2) * 36 + x4 * 4]);
        s2 += dot4(gv, *(const float4*)&T[(kb + 4) * 36 + x4 * 4]);
        s3 += dot4(gv, *(const float4*)&T[(kb + 6) * 36 + x4 * 4]);
      }
      // flat f = p*512+c, p=i*32+k -> catT[n=(par*512+c)][col=i*16+kq*4+j]
      short4v o;
      o[0] = (short)f2bf(s0); o[1] = (short)f2bf(s1);
      o[2] = (short)f2bf(s2); o[3] = (short)f2bf(s3);
      *(short4v*)&catT[(par * 512 + c) * 1024 + i * 16 + kq * 4] = o;
    }
  } else {
    // CSA: one wave per location p
    int wv = threadIdx.x >> 6;
    int lane = threadIdx.x & 63;
    int p = (blockIdx.x - 512) * 4 + wv;
    int h = p >> 5, w = p & 31;
    int c0 = lane * 8;
    float4 ce0 = *(const float4*)&sigT[p * 512 + c0];
    float4 ce1 = *(const float4*)&sigT[p * 512 + c0 + 4];
    int qoff[9];
    float s[9];
    #pragma unroll
    for (int dd = 0; dd < 9; dd++) {
      int hh = h + dd / 3 - 1, ww = w + (dd % 3) - 1;
      bool v = (hh >= 0) && (hh < 32) && (ww >= 0) && (ww < 32);
      qoff[dd] = v ? (hh * 32 + ww) * 512 : -1;
      float a = 0.0f;
      if (v) {
        float4 n0 = *(const float4*)&sigT[qoff[dd] + c0];
        float4 n1 = *(const float4*)&sigT[qoff[dd] + c0 + 4];
        a = dot4(ce0, n0) + dot4(ce1, n1);
      }
      #pragma unroll
      for (int off = 32; off >= 1; off >>= 1) a += __shfl_xor(a, off);
      s[dd] = a;
    }
    float mx = -1e30f;
    #pragma unroll
    for (int dd = 0; dd < 9; dd++) { s[dd] *= (1.0f / 512.0f); mx = fmaxf(mx, s[dd]); }
    float tot = 0.0f;
    #pragma unroll
    for (int dd = 0; dd < 9; dd++) { s[dd] = __expf(s[dd] - mx); tot += s[dd]; }
    float inv = 1.0f / tot;
    float o[8] = {0, 0, 0, 0, 0, 0, 0, 0};
    #pragma unroll
    for (int dd = 0; dd < 9; dd++) {
      if (qoff[dd] >= 0) {
        float att = s[dd] * inv;
        float4 r0 = *(const float4*)&out32T[qoff[dd] + c0];
        float4 r1 = *(const float4*)&out32T[qoff[dd] + c0 + 4];
        o[0] += att * r0.x; o[1] += att * r0.y; o[2] += att * r0.z; o[3] += att * r0.w;
        o[4] += att * r1.x; o[5] += att * r1.y; o[6] += att * r1.z; o[7] += att * r1.w;
      }
    }
    // flat f = 524288 + p*512 + c -> catT[n=(p&1)*512+c][col=512+(p>>1)]
    int kcol = 512 + (p >> 1);
    int nbase = (p & 1) * 512 + c0;
    #pragma unroll
    for (int q = 0; q < 8; q++) catT[(nbase + q) * 1024 + kcol] = f2bf(o[q]);
  }
}

// --- K4: bf16 MFMA GEMM y[512][1024] = Abf x catT^T, 32x32x16 MFMA ---
// 512 blocks (16m x 32n) x 4 kz-waves, K=256 each (16-MFMA chain); LDS reduce.
__global__ void k_gemm(const unsigned short* __restrict__ Abf,
                       const unsigned short* __restrict__ Bbf,
                       float* __restrict__ y) {
  __shared__ float red[3][1024];
  int tid = threadIdx.x;
  int wv = tid >> 6, lane = tid & 63;   // wv = kz 0..3
  int bm = (blockIdx.x >> 5) * 32;
  int nn = (blockIdx.x & 31) * 32;
  int l32 = lane & 31, half = lane >> 5;
  const short8* ap = (const short8*)(Abf + (bm + l32) * 1024 + wv * 256 + half * 8);
  const short8* bp = (const short8*)(Bbf + (nn + l32) * 1024 + wv * 256 + half * 8);
  floatx16 acc = {};
  #pragma unroll
  for (int ks = 0; ks < 16; ks++) {
    short8 a = ap[ks * 2];              // 16 k per step
    short8 b = bp[ks * 2];
    acc = __builtin_amdgcn_mfma_f32_32x32x16_bf16(a, b, acc, 0, 0, 0);
  }
  if (wv != 0) {
    #pragma unroll
    for (int r4 = 0; r4 < 4; r4++) {
      float4 v = make_float4(acc[r4 * 4], acc[r4 * 4 + 1], acc[r4 * 4 + 2], acc[r4 * 4 + 3]);
      *(float4*)&red[wv - 1][lane * 16 + r4 * 4] = v;
    }
  }
  __syncthreads();
  if (wv == 0) {
    // C/D layout: col = lane&31, row = (reg&3) + 8*(reg>>2) + 4*half
    #pragma unroll
    for (int r = 0; r < 16; r++) {
      float v = acc[r] + red[0][lane * 16 + r] + red[1][lane * 16 + r] + red[2][lane * 16 + r];
      int rowm = (r & 3) + 8 * (r >> 2) + 4 * half;
      y[(bm + rowm) * 1024 + nn + l32] = v;
    }
  }
}

// --- K5: instance norm (biased var) + LeakyReLU(0.2) ---
__global__ void k_inorm(const float* __restrict__ y, float* __restrict__ out) {
  __shared__ float sm4[4];
  __shared__ float vrow[1024];
  int o = blockIdx.x;
  int tid = threadIdx.x;
  float4 v4 = *(const float4*)&y[o * 1024 + tid * 4];
  *(float4*)&vrow[tid * 4] = v4;
  float s = v4.x + v4.y + v4.z + v4.w;
  float q = v4.x * v4.x + v4.y * v4.y + v4.z * v4.z + v4.w * v4.w;
  float ts = block_reduce_256(s, sm4);
  float tq = block_reduce_256(q, sm4);
  float mean = ts * (1.0f / 1024.0f);
  float var = tq * (1.0f / 1024.0f) - mean * mean;
  float inv = rsqrtf(var + 1e-5f);
  float4 w4 = *(const float4*)&vrow[tid * 4];
  float4 r4;
  float a0 = (w4.x - mean) * inv; r4.x = a0 >= 0.0f ? a0 : 0.2f * a0;
  float a1 = (w4.y - mean) * inv; r4.y = a1 >= 0.0f ? a1 : 0.2f * a1;
  float a2 = (w4.z - mean) * inv; r4.z = a2 >= 0.0f ? a2 : 0.2f * a2;
  float a3 = (w4.w - mean) * inv; r4.w = a3 >= 0.0f ? a3 : 0.2f * a3;
  *(float4*)&out[o * 1024 + tid * 4] = r4;
}

extern "C" void kernel_launch(void* const* d_in, const int* in_sizes, int n_in,
                              void* d_out, int out_size, void* d_ws, size_t ws_size,
                              hipStream_t stream) {
  const float* x      = (const float*)d_in[0];  // (1,512,32,32)
  const float* w_se1  = (const float*)d_in[1];  // (32,512)
  const float* w_se2  = (const float*)d_in[2];  // (512,32)
  const float* w_down = (const float*)d_in[3];  // (512,1024,1,1)
  float* out = (float*)d_out;                   // (1,512,32,32)

  float* ws = (float*)d_ws;
  float* smean  = ws;                        // 512 (+pad to 1024)
  float* out32  = ws + 1024;                 // 524288  [c][hw]
  float* out32T = ws + 525312;               // 524288  [hw][c]
  float* sigT   = ws + 1049600;              // 524288  [hw][c]
  unsigned short* catT = (unsigned short*)(ws + 1573888);  // 1024x1024 bf16 [n][k]
  unsigned short* Abf  = (unsigned short*)(ws + 2098176);  // 512x1024 bf16 [m][k]
  float* ybuf   = ws + 2360320;              // 524288

  k_mean_cvt<<<768, 256, 0, stream>>>(x, smean, w_down, Abf);
  k_apply<<<dim3(32, 16), 256, 0, stream>>>(x, smean, w_se1, w_se2, out32, out32T, sigT);
  k_gausscsa<<<768, 256, 0, stream>>>(out32, sigT, out32T, catT);
  k_gemm<<<512, 256, 0, stream>>>(Abf, catT, ybuf);
  k_inorm<<<512, 256, 0, stream>>>(ybuf, out);
}